// Round 1
// baseline (1892.326 us; speedup 1.0000x reference)
//
#include <hip/hip_runtime.h>
#include <hip/hip_bf16.h>
#include <math.h>

#define N_NODES 50000
#define N_EDGES 800000
#define NH 4
#define HC 256
#define TOT_E (N_EDGES + N_NODES)

static __device__ __forceinline__ float lrelu(float x) { return x >= 0.f ? x : 0.2f * x; }

// ---------------- CSR build (counting sort by dst) ----------------
__global__ __launch_bounds__(256) void count_kernel(const int* __restrict__ ei,
                                                    int* __restrict__ cnt) {
    int i = blockIdx.x * blockDim.x + threadIdx.x;
    if (i >= TOT_E) return;
    int dst = (i < N_EDGES) ? ei[N_EDGES + i] : (i - N_EDGES);  // self-loops appended
    atomicAdd(&cnt[dst], 1);
}

__global__ __launch_bounds__(256) void scan_kernel(const int* __restrict__ cnt,
                                                   int* __restrict__ offs) {
    __shared__ int sm[256];
    const int t = threadIdx.x;
    int carry = 0;
    for (int base = 0; base < N_NODES; base += 256) {
        int v = (base + t < N_NODES) ? cnt[base + t] : 0;
        sm[t] = v;
        __syncthreads();
#pragma unroll
        for (int d = 1; d < 256; d <<= 1) {
            int add = (t >= d) ? sm[t - d] : 0;
            __syncthreads();
            sm[t] += add;
            __syncthreads();
        }
        if (base + t < N_NODES) offs[base + t] = carry + sm[t] - v;  // exclusive
        carry += sm[255];
        __syncthreads();
    }
    if (t == 0) offs[N_NODES] = carry;
}

__global__ __launch_bounds__(256) void scatter_kernel(const int* __restrict__ ei,
                                                      const int* __restrict__ offs,
                                                      int* __restrict__ cursor,
                                                      int* __restrict__ ssrc) {
    int i = blockIdx.x * blockDim.x + threadIdx.x;
    if (i >= TOT_E) return;
    int src, dst;
    if (i < N_EDGES) { src = ei[i]; dst = ei[N_EDGES + i]; }
    else             { src = i - N_EDGES; dst = src; }
    int pos = offs[dst] + atomicAdd(&cursor[dst], 1);
    ssrc[pos] = src;
}

// ---------------- fp32 GEMM: C[M,256] = A[M,K] @ B[K,256] ----------------
__global__ __launch_bounds__(256) void gemm_kernel(const float* __restrict__ A,
                                                   const float* __restrict__ B,
                                                   float* __restrict__ C,
                                                   int M, int K) {
    __shared__ float As[16][64];
    __shared__ float Bs[16][64];
    const int t = threadIdx.x;
    const int tx = t & 15, ty = t >> 4;
    const int bm = blockIdx.x * 64;
    const int bn = blockIdx.y * 64;
    const int ar = t >> 2, ak = (t & 3) << 2;   // A staging: row, k-quad
    const int bkk = t >> 6, bnn = t & 63;       // B staging
    float acc[4][4] = {{0.f}};
    const int arow = bm + ar;
    for (int k0 = 0; k0 < K; k0 += 16) {
        float4 a4 = make_float4(0.f, 0.f, 0.f, 0.f);
        if (arow < M) a4 = *(const float4*)(A + (size_t)arow * K + (k0 + ak));
        As[ak + 0][ar] = a4.x; As[ak + 1][ar] = a4.y;
        As[ak + 2][ar] = a4.z; As[ak + 3][ar] = a4.w;
#pragma unroll
        for (int r = 0; r < 4; ++r)
            Bs[bkk + 4 * r][bnn] = B[(size_t)(k0 + bkk + 4 * r) * HC + bn + bnn];
        __syncthreads();
#pragma unroll
        for (int kk = 0; kk < 16; ++kk) {
            float4 av = *(const float4*)&As[kk][ty << 2];
            float4 bv = *(const float4*)&Bs[kk][tx << 2];
            float a[4] = {av.x, av.y, av.z, av.w};
            float b[4] = {bv.x, bv.y, bv.z, bv.w};
#pragma unroll
            for (int i = 0; i < 4; ++i)
#pragma unroll
                for (int j = 0; j < 4; ++j)
                    acc[i][j] = fmaf(a[i], b[j], acc[i][j]);
        }
        __syncthreads();
    }
#pragma unroll
    for (int i = 0; i < 4; ++i) {
        int row = bm + (ty << 2) + i;
        if (row < M)
            *(float4*)(C + (size_t)row * HC + bn + (tx << 2)) =
                make_float4(acc[i][0], acc[i][1], acc[i][2], acc[i][3]);
    }
}

// ---------------- per-node attention logits: al_s/al_d [N,H] ----------------
__global__ __launch_bounds__(256) void al_kernel(const float* __restrict__ h,
                                                 const float* __restrict__ a_s,
                                                 const float* __restrict__ a_d,
                                                 float* __restrict__ als,
                                                 float* __restrict__ ald) {
    const int lane = threadIdx.x & 63;
    const int v = (blockIdx.x << 2) + (threadIdx.x >> 6);
    if (v >= N_NODES) return;
    const int hh = lane >> 4;  // head; lane covers channels [4*lane, 4*lane+4)
    float4 hv = *(const float4*)(h + (size_t)v * HC + lane * 4);
    float4 s4 = *(const float4*)(a_s + lane * 4);
    float4 d4 = *(const float4*)(a_d + lane * 4);
    float ps = hv.x * s4.x + hv.y * s4.y + hv.z * s4.z + hv.w * s4.w;
    float pd = hv.x * d4.x + hv.y * d4.y + hv.z * d4.z + hv.w * d4.w;
#pragma unroll
    for (int d = 1; d < 16; d <<= 1) {  // reduce over the 16 lanes of one head
        ps += __shfl_xor(ps, d, 64);
        pd += __shfl_xor(pd, d, 64);
    }
    if ((lane & 15) == 0) { als[v * NH + hh] = ps; ald[v * NH + hh] = pd; }
}

// ---------------- GAT aggregation: one wave per dst, online softmax ----------------
__global__ __launch_bounds__(256) void gat_edge_kernel(const float* __restrict__ h,
                                                       const int* __restrict__ offs,
                                                       const int* __restrict__ ssrc,
                                                       const float* __restrict__ als,
                                                       const float* __restrict__ ald,
                                                       const float* __restrict__ bias,
                                                       float* __restrict__ out) {
    const int lane = threadIdx.x & 63;
    const int v = (blockIdx.x << 2) + (threadIdx.x >> 6);
    if (v >= N_NODES) return;
    const int hh = lane >> 4;
    const float aldv = ald[v * NH + hh];
    float m = -INFINITY, s = 0.f;
    float ax = 0.f, ay = 0.f, az = 0.f, aw = 0.f;
    const int beg = offs[v], end = offs[v + 1];
    for (int i = beg; i < end; ++i) {
        const int src = ssrc[i];
        float e = lrelu(als[src * NH + hh] + aldv);
        float4 hv = *(const float4*)(h + (size_t)src * HC + lane * 4);
        if (e > m) {  // rescale running state; exp(m - e) == 0 on first edge
            const float r = __expf(m - e);
            s = s * r + 1.f;
            ax = fmaf(ax, r, hv.x); ay = fmaf(ay, r, hv.y);
            az = fmaf(az, r, hv.z); aw = fmaf(aw, r, hv.w);
            m = e;
        } else {
            const float ex = __expf(e - m);
            s += ex;
            ax = fmaf(ex, hv.x, ax); ay = fmaf(ex, hv.y, ay);
            az = fmaf(ex, hv.z, az); aw = fmaf(ex, hv.w, aw);
        }
    }
    const float inv = 1.f / (s + 1e-16f);
    float4 b4 = *(const float4*)(bias + lane * 4);
    *(float4*)(out + (size_t)v * HC + lane * 4) =
        make_float4(fmaf(ax, inv, b4.x), fmaf(ay, inv, b4.y),
                    fmaf(az, inv, b4.z), fmaf(aw, inv, b4.w));
}

// ---------------- BatchNorm ----------------
__global__ __launch_bounds__(256) void bn_stats_kernel(const float* __restrict__ y,
                                                       double* __restrict__ sum,
                                                       double* __restrict__ sqsum) {
    const int t = threadIdx.x;  // channel
    const int r0 = blockIdx.x * 128;
    const int r1 = min(r0 + 128, N_NODES);
    float s = 0.f, q = 0.f;
    for (int r = r0; r < r1; ++r) {
        float v = y[(size_t)r * HC + t];
        s += v;
        q = fmaf(v, v, q);
    }
    atomicAdd(&sum[t], (double)s);
    atomicAdd(&sqsum[t], (double)q);
}

__global__ void bn_finalize_kernel(const double* __restrict__ sum,
                                   const double* __restrict__ sqsum,
                                   const float* __restrict__ g,
                                   const float* __restrict__ be,
                                   float* __restrict__ scale,
                                   float* __restrict__ shift) {
    int t = threadIdx.x;
    double mean = sum[t] / (double)N_NODES;
    double var = sqsum[t] / (double)N_NODES - mean * mean;
    float sc = g[t] * rsqrtf((float)var + 1e-5f);
    scale[t] = sc;
    shift[t] = be[t] - (float)mean * sc;
}

__global__ __launch_bounds__(256) void bn_apply_relu_kernel(float* __restrict__ y,
                                                            const float* __restrict__ scale,
                                                            const float* __restrict__ shift) {
    int i = blockIdx.x * blockDim.x + threadIdx.x;  // over N*64 float4s
    if (i >= N_NODES * 64) return;
    int c = (i & 63) << 2;
    float4 v = ((float4*)y)[i];
    v.x = fmaxf(0.f, fmaf(v.x, scale[c + 0], shift[c + 0]));
    v.y = fmaxf(0.f, fmaf(v.y, scale[c + 1], shift[c + 1]));
    v.z = fmaxf(0.f, fmaf(v.z, scale[c + 2], shift[c + 2]));
    v.w = fmaxf(0.f, fmaf(v.w, scale[c + 3], shift[c + 3]));
    ((float4*)y)[i] = v;
}

// ---------------- final linear: out[N,32] = y[N,256] @ Wl[256,32] + bl ----------------
__global__ __launch_bounds__(256) void linear_kernel(const float* __restrict__ y,
                                                     const float* __restrict__ Wl,
                                                     const float* __restrict__ bl,
                                                     float* __restrict__ out) {
    __shared__ float Wls[256 * 32];
    const int t = threadIdx.x;
    for (int i = t; i < 256 * 32; i += 256) Wls[i] = Wl[i];
    __syncthreads();
    int gid = blockIdx.x * 256 + t;
    if (gid >= N_NODES * 32) return;
    int n = gid >> 5, j = gid & 31;
    float acc = bl[j];
    const float4* yrow = (const float4*)(y + (size_t)n * HC);
#pragma unroll
    for (int k4 = 0; k4 < 64; ++k4) {
        float4 y4 = yrow[k4];
        int k = k4 << 2;
        acc = fmaf(y4.x, Wls[(k + 0) * 32 + j], acc);
        acc = fmaf(y4.y, Wls[(k + 1) * 32 + j], acc);
        acc = fmaf(y4.z, Wls[(k + 2) * 32 + j], acc);
        acc = fmaf(y4.w, Wls[(k + 3) * 32 + j], acc);
    }
    out[gid] = acc;
}

extern "C" void kernel_launch(void* const* d_in, const int* in_sizes, int n_in,
                              void* d_out, int out_size, void* d_ws, size_t ws_size,
                              hipStream_t stream) {
    const float* x     = (const float*)d_in[0];
    const int* ei_sp   = (const int*)d_in[1];
    const int* ei_tp   = (const int*)d_in[2];
    const float* Wl    = (const float*)d_in[27];
    const float* bl    = (const float*)d_in[28];

    // ---- workspace layout ----
    char* ws = (char*)d_ws;
    size_t off = 0;
    auto alloc = [&](size_t bytes) -> char* {
        char* p = ws + off;
        off = (off + bytes + 255) & ~(size_t)255;
        return p;
    };
    float* buf0    = (float*)alloc((size_t)N_NODES * HC * 4);  // gemm output h
    float* buf1    = (float*)alloc((size_t)N_NODES * HC * 4);  // gat output / next input
    float* als     = (float*)alloc((size_t)N_NODES * NH * 4);
    float* ald     = (float*)alloc((size_t)N_NODES * NH * 4);
    int*   offs_sp = (int*)alloc((size_t)(N_NODES + 1) * 4);
    int*   offs_tp = (int*)alloc((size_t)(N_NODES + 1) * 4);
    int*   src_sp  = (int*)alloc((size_t)TOT_E * 4);
    int*   src_tp  = (int*)alloc((size_t)TOT_E * 4);
    int*   cnt     = (int*)alloc((size_t)N_NODES * 4);
    double* bnsum  = (double*)alloc(256 * 8 * 2);  // sum + sqsum contiguous
    double* bnsq   = bnsum + 256;
    float* scale   = (float*)alloc(256 * 4);
    float* shift   = (float*)alloc(256 * 4);
    (void)ws_size; (void)in_sizes; (void)n_in; (void)out_size;

    const int EB = (TOT_E + 255) / 256;

    // ---- build CSR for both edge types (once per call) ----
    hipMemsetAsync(cnt, 0, (size_t)N_NODES * 4, stream);
    count_kernel<<<EB, 256, 0, stream>>>(ei_sp, cnt);
    scan_kernel<<<1, 256, 0, stream>>>(cnt, offs_sp);
    hipMemsetAsync(cnt, 0, (size_t)N_NODES * 4, stream);
    scatter_kernel<<<EB, 256, 0, stream>>>(ei_sp, offs_sp, cnt, src_sp);

    hipMemsetAsync(cnt, 0, (size_t)N_NODES * 4, stream);
    count_kernel<<<EB, 256, 0, stream>>>(ei_tp, cnt);
    scan_kernel<<<1, 256, 0, stream>>>(cnt, offs_tp);
    hipMemsetAsync(cnt, 0, (size_t)N_NODES * 4, stream);
    scatter_kernel<<<EB, 256, 0, stream>>>(ei_tp, offs_tp, cnt, src_tp);

    // ---- 4 GAT + BN + ReLU layers ----
    const int NB4 = (N_NODES + 3) / 4;            // wave-per-node kernels
    const dim3 ggrid((N_NODES + 63) / 64, 4);     // gemm grid
    for (int L = 0; L < 4; ++L) {
        const float* in = (L == 0) ? x : buf1;
        const int K = (L == 0) ? 128 : 256;
        const int* offs = (L < 2) ? offs_sp : offs_tp;
        const int* ssrc = (L < 2) ? src_sp : src_tp;
        const int base = 3 + L * 6;
        const float* W  = (const float*)d_in[base + 0];
        const float* as_ = (const float*)d_in[base + 1];
        const float* ad_ = (const float*)d_in[base + 2];
        const float* b_  = (const float*)d_in[base + 3];
        const float* g_  = (const float*)d_in[base + 4];
        const float* be_ = (const float*)d_in[base + 5];

        gemm_kernel<<<ggrid, 256, 0, stream>>>(in, W, buf0, N_NODES, K);
        al_kernel<<<NB4, 256, 0, stream>>>(buf0, as_, ad_, als, ald);
        gat_edge_kernel<<<NB4, 256, 0, stream>>>(buf0, offs, ssrc, als, ald, b_, buf1);

        hipMemsetAsync(bnsum, 0, 256 * 8 * 2, stream);
        bn_stats_kernel<<<(N_NODES + 127) / 128, 256, 0, stream>>>(buf1, bnsum, bnsq);
        bn_finalize_kernel<<<1, 256, 0, stream>>>(bnsum, bnsq, g_, be_, scale, shift);
        bn_apply_relu_kernel<<<(N_NODES * 64 + 255) / 256, 256, 0, stream>>>(buf1, scale, shift);
    }

    // ---- final linear ----
    linear_kernel<<<(N_NODES * 32 + 255) / 256, 256, 0, stream>>>(buf1, Wl, bl, (float*)d_out);
}

// Round 4
// 1482.165 us; speedup vs baseline: 1.2767x; 1.2767x over previous
//
#include <hip/hip_runtime.h>
#include <hip/hip_bf16.h>
#include <math.h>

#define N_NODES 50000
#define N_EDGES 800000
#define NH 4
#define HC 256
#define TOT_E (N_EDGES + N_NODES)
#define SCAN_NB ((N_NODES + 255) / 256)

static __device__ __forceinline__ float lrelu(float x) { return x >= 0.f ? x : 0.2f * x; }

// ---------------- CSR build (counting sort by dst) ----------------
__global__ __launch_bounds__(256) void count_kernel(const int* __restrict__ ei,
                                                    int* __restrict__ cnt) {
    int i = blockIdx.x * blockDim.x + threadIdx.x;
    if (i >= TOT_E) return;
    int dst = (i < N_EDGES) ? ei[N_EDGES + i] : (i - N_EDGES);  // self-loops appended
    atomicAdd(&cnt[dst], 1);
}

// device-wide exclusive scan over cnt[N_NODES] -> offs, 3 kernels
__global__ __launch_bounds__(256) void scan1_kernel(const int* __restrict__ cnt,
                                                    int* __restrict__ offs,
                                                    int* __restrict__ bsum) {
    __shared__ int sm[256];
    const int t = threadIdx.x;
    const int base = blockIdx.x * 256;
    int v = (base + t < N_NODES) ? cnt[base + t] : 0;
    sm[t] = v;
    __syncthreads();
#pragma unroll
    for (int d = 1; d < 256; d <<= 1) {
        int add = (t >= d) ? sm[t - d] : 0;
        __syncthreads();
        sm[t] += add;
        __syncthreads();
    }
    if (base + t < N_NODES) offs[base + t] = sm[t] - v;  // local exclusive
    if (t == 255) bsum[blockIdx.x] = sm[255];
}

__global__ __launch_bounds__(256) void scan2_kernel(int* __restrict__ bsum,
                                                    int* __restrict__ total) {
    __shared__ int sm[256];
    const int t = threadIdx.x;
    int v = (t < SCAN_NB) ? bsum[t] : 0;
    sm[t] = v;
    __syncthreads();
#pragma unroll
    for (int d = 1; d < 256; d <<= 1) {
        int add = (t >= d) ? sm[t - d] : 0;
        __syncthreads();
        sm[t] += add;
        __syncthreads();
    }
    if (t < SCAN_NB) bsum[t] = sm[t] - v;  // exclusive block offsets
    if (t == 255) *total = sm[255];        // == TOT_E
}

__global__ __launch_bounds__(256) void scan3_kernel(int* __restrict__ offs,
                                                    const int* __restrict__ bsum) {
    int i = blockIdx.x * blockDim.x + threadIdx.x;
    if (i < N_NODES) offs[i] += bsum[i >> 8];
}

__global__ __launch_bounds__(256) void scatter_kernel(const int* __restrict__ ei,
                                                      const int* __restrict__ offs,
                                                      int* __restrict__ cursor,
                                                      int* __restrict__ ssrc) {
    int i = blockIdx.x * blockDim.x + threadIdx.x;
    if (i >= TOT_E) return;
    int src, dst;
    if (i < N_EDGES) { src = ei[i]; dst = ei[N_EDGES + i]; }
    else             { src = i - N_EDGES; dst = src; }
    int pos = offs[dst] + atomicAdd(&cursor[dst], 1);
    ssrc[pos] = src;
}

// ---------------- fp32 GEMM: C[M,256] = A[M,K] @ B[K,256] ----------------
// 128x128 tile, 8x8 microtile, 256 threads (16x16)
__global__ __launch_bounds__(256) void gemm_kernel(const float* __restrict__ A,
                                                   const float* __restrict__ B,
                                                   float* __restrict__ C,
                                                   int M, int K) {
    __shared__ float As[16][128];  // [k][m]
    __shared__ float Bs[16][128];  // [k][n]
    const int t = threadIdx.x;
    const int tx = t & 15, ty = t >> 4;
    const int bm = blockIdx.x * 128;
    const int bn = blockIdx.y * 128;
    const int ar = t >> 2;          // 0..63   A staging row within half
    const int ak = (t & 3) << 2;    // 0,4,8,12
    const int bk = t >> 5;          // 0..7    B staging k within half
    const int bn4 = (t & 31) << 2;  // 0..124
    float acc[8][8] = {{0.f}};
    for (int k0 = 0; k0 < K; k0 += 16) {
#pragma unroll
        for (int r = 0; r < 2; ++r) {
            int row = bm + r * 64 + ar;
            float4 a4 = make_float4(0.f, 0.f, 0.f, 0.f);
            if (row < M) a4 = *(const float4*)(A + (size_t)row * K + k0 + ak);
            As[ak + 0][r * 64 + ar] = a4.x;
            As[ak + 1][r * 64 + ar] = a4.y;
            As[ak + 2][r * 64 + ar] = a4.z;
            As[ak + 3][r * 64 + ar] = a4.w;
        }
#pragma unroll
        for (int r = 0; r < 2; ++r) {
            int kk = r * 8 + bk;
            *(float4*)&Bs[kk][bn4] = *(const float4*)(B + (size_t)(k0 + kk) * HC + bn + bn4);
        }
        __syncthreads();
#pragma unroll
        for (int kk = 0; kk < 16; ++kk) {
            float a[8], b[8];
            *(float4*)&a[0] = *(const float4*)&As[kk][ty * 8];
            *(float4*)&a[4] = *(const float4*)&As[kk][ty * 8 + 4];
            *(float4*)&b[0] = *(const float4*)&Bs[kk][tx * 8];
            *(float4*)&b[4] = *(const float4*)&Bs[kk][tx * 8 + 4];
#pragma unroll
            for (int i = 0; i < 8; ++i)
#pragma unroll
                for (int j = 0; j < 8; ++j)
                    acc[i][j] = fmaf(a[i], b[j], acc[i][j]);
        }
        __syncthreads();
    }
#pragma unroll
    for (int i = 0; i < 8; ++i) {
        int row = bm + ty * 8 + i;
        if (row < M) {
            *(float4*)(C + (size_t)row * HC + bn + tx * 8) =
                make_float4(acc[i][0], acc[i][1], acc[i][2], acc[i][3]);
            *(float4*)(C + (size_t)row * HC + bn + tx * 8 + 4) =
                make_float4(acc[i][4], acc[i][5], acc[i][6], acc[i][7]);
        }
    }
}

// ---------------- per-node attention logits: al_s/al_d [N,H] ----------------
__global__ __launch_bounds__(256) void al_kernel(const float* __restrict__ h,
                                                 const float* __restrict__ a_s,
                                                 const float* __restrict__ a_d,
                                                 float* __restrict__ als,
                                                 float* __restrict__ ald) {
    const int lane = threadIdx.x & 63;
    const int v = (blockIdx.x << 2) + (threadIdx.x >> 6);
    if (v >= N_NODES) return;
    const int hh = lane >> 4;  // head; lane covers channels [4*lane, 4*lane+4)
    float4 hv = *(const float4*)(h + (size_t)v * HC + lane * 4);
    float4 s4 = *(const float4*)(a_s + lane * 4);
    float4 d4 = *(const float4*)(a_d + lane * 4);
    float ps = hv.x * s4.x + hv.y * s4.y + hv.z * s4.z + hv.w * s4.w;
    float pd = hv.x * d4.x + hv.y * d4.y + hv.z * d4.z + hv.w * d4.w;
#pragma unroll
    for (int d = 1; d < 16; d <<= 1) {  // reduce over the 16 lanes of one head
        ps += __shfl_xor(ps, d, 64);
        pd += __shfl_xor(pd, d, 64);
    }
    if ((lane & 15) == 0) { als[v * NH + hh] = ps; ald[v * NH + hh] = pd; }
}

// ---------------- GAT aggregation: one wave per dst, online softmax ----------------
// branchless update + 1-deep software prefetch of (src, h-row, al_s)
__global__ __launch_bounds__(256) void gat_edge_kernel(const float* __restrict__ h,
                                                       const int* __restrict__ offs,
                                                       const int* __restrict__ ssrc,
                                                       const float* __restrict__ als,
                                                       const float* __restrict__ ald,
                                                       const float* __restrict__ bias,
                                                       float* __restrict__ out) {
    const int lane = threadIdx.x & 63;
    const int v = (blockIdx.x << 2) + (threadIdx.x >> 6);
    if (v >= N_NODES) return;
    const int hh = lane >> 4;
    const float aldv = ald[v * NH + hh];
    float m = -INFINITY, s = 0.f;
    float ax = 0.f, ay = 0.f, az = 0.f, aw = 0.f;
    const int beg = offs[v], end = offs[v + 1];
    // degree >= 1 always (self-loop)
    int src = ssrc[beg];
    float4 hv = *(const float4*)(h + (size_t)src * HC + lane * 4);
    float alv = als[src * NH + hh];
    for (int i = beg; i < end; ++i) {
        float4 nhv = make_float4(0.f, 0.f, 0.f, 0.f);
        float nalv = 0.f;
        if (i + 1 < end) {  // prefetch next edge while computing this one
            int nsrc = ssrc[i + 1];
            nhv = *(const float4*)(h + (size_t)nsrc * HC + lane * 4);
            nalv = als[nsrc * NH + hh];
        }
        const float e = lrelu(alv + aldv);
        const float mn = fmaxf(m, e);
        const float r = __expf(m - mn);   // 0 on first edge (m = -inf)
        const float ex = __expf(e - mn);
        s = fmaf(s, r, ex);
        ax = fmaf(ax, r, ex * hv.x);
        ay = fmaf(ay, r, ex * hv.y);
        az = fmaf(az, r, ex * hv.z);
        aw = fmaf(aw, r, ex * hv.w);
        m = mn;
        hv = nhv;
        alv = nalv;
    }
    const float inv = 1.f / (s + 1e-16f);
    float4 b4 = *(const float4*)(bias + lane * 4);
    *(float4*)(out + (size_t)v * HC + lane * 4) =
        make_float4(fmaf(ax, inv, b4.x), fmaf(ay, inv, b4.y),
                    fmaf(az, inv, b4.z), fmaf(aw, inv, b4.w));
}

// ---------------- BatchNorm ----------------
__global__ __launch_bounds__(256) void bn_stats_kernel(const float* __restrict__ y,
                                                       double* __restrict__ sum,
                                                       double* __restrict__ sqsum) {
    const int t = threadIdx.x;  // channel
    const int r0 = blockIdx.x * 128;
    const int r1 = min(r0 + 128, N_NODES);
    float s = 0.f, q = 0.f;
    for (int r = r0; r < r1; ++r) {
        float v = y[(size_t)r * HC + t];
        s += v;
        q = fmaf(v, v, q);
    }
    atomicAdd(&sum[t], (double)s);
    atomicAdd(&sqsum[t], (double)q);
}

__global__ void bn_finalize_kernel(const double* __restrict__ sum,
                                   const double* __restrict__ sqsum,
                                   const float* __restrict__ g,
                                   const float* __restrict__ be,
                                   float* __restrict__ scale,
                                   float* __restrict__ shift) {
    int t = threadIdx.x;
    double mean = sum[t] / (double)N_NODES;
    double var = sqsum[t] / (double)N_NODES - mean * mean;
    float sc = g[t] * rsqrtf((float)var + 1e-5f);
    scale[t] = sc;
    shift[t] = be[t] - (float)mean * sc;
}

__global__ __launch_bounds__(256) void bn_apply_relu_kernel(float* __restrict__ y,
                                                            const float* __restrict__ scale,
                                                            const float* __restrict__ shift) {
    int i = blockIdx.x * blockDim.x + threadIdx.x;  // over N*64 float4s
    if (i >= N_NODES * 64) return;
    int c = (i & 63) << 2;
    float4 v = ((float4*)y)[i];
    v.x = fmaxf(0.f, fmaf(v.x, scale[c + 0], shift[c + 0]));
    v.y = fmaxf(0.f, fmaf(v.y, scale[c + 1], shift[c + 1]));
    v.z = fmaxf(0.f, fmaf(v.z, scale[c + 2], shift[c + 2]));
    v.w = fmaxf(0.f, fmaf(v.w, scale[c + 3], shift[c + 3]));
    ((float4*)y)[i] = v;
}

// ---------------- final linear: out[N,32] = y[N,256] @ Wl[256,32] + bl ----------------
__global__ __launch_bounds__(256) void linear_kernel(const float* __restrict__ y,
                                                     const float* __restrict__ Wl,
                                                     const float* __restrict__ bl,
                                                     float* __restrict__ out) {
    __shared__ float Wls[256 * 32];
    const int t = threadIdx.x;
    for (int i = t; i < 256 * 32; i += 256) Wls[i] = Wl[i];
    __syncthreads();
    int gid = blockIdx.x * 256 + t;
    if (gid >= N_NODES * 32) return;
    int n = gid >> 5, j = gid & 31;
    float acc = bl[j];
    const float4* yrow = (const float4*)(y + (size_t)n * HC);
#pragma unroll
    for (int k4 = 0; k4 < 64; ++k4) {
        float4 y4 = yrow[k4];
        int k = k4 << 2;
        acc = fmaf(y4.x, Wls[(k + 0) * 32 + j], acc);
        acc = fmaf(y4.y, Wls[(k + 1) * 32 + j], acc);
        acc = fmaf(y4.z, Wls[(k + 2) * 32 + j], acc);
        acc = fmaf(y4.w, Wls[(k + 3) * 32 + j], acc);
    }
    out[gid] = acc;
}

extern "C" void kernel_launch(void* const* d_in, const int* in_sizes, int n_in,
                              void* d_out, int out_size, void* d_ws, size_t ws_size,
                              hipStream_t stream) {
    const float* x     = (const float*)d_in[0];
    const int* ei_sp   = (const int*)d_in[1];
    const int* ei_tp   = (const int*)d_in[2];
    const float* Wl    = (const float*)d_in[27];
    const float* bl    = (const float*)d_in[28];

    // ---- workspace layout ----
    char* ws = (char*)d_ws;
    size_t off = 0;
    auto alloc = [&](size_t bytes) -> char* {
        char* p = ws + off;
        off = (off + bytes + 255) & ~(size_t)255;
        return p;
    };
    float* buf0    = (float*)alloc((size_t)N_NODES * HC * 4);  // gemm output h
    float* buf1    = (float*)alloc((size_t)N_NODES * HC * 4);  // gat output / next input
    float* als     = (float*)alloc((size_t)N_NODES * NH * 4);
    float* ald     = (float*)alloc((size_t)N_NODES * NH * 4);
    int*   offs_sp = (int*)alloc((size_t)(N_NODES + 1) * 4);
    int*   offs_tp = (int*)alloc((size_t)(N_NODES + 1) * 4);
    int*   src_sp  = (int*)alloc((size_t)TOT_E * 4);
    int*   src_tp  = (int*)alloc((size_t)TOT_E * 4);
    int*   cnt     = (int*)alloc((size_t)N_NODES * 4);
    int*   bsum    = (int*)alloc((size_t)SCAN_NB * 4);
    double* bnsum  = (double*)alloc(256 * 8 * 2);  // sum + sqsum contiguous
    double* bnsq   = bnsum + 256;
    float* scale   = (float*)alloc(256 * 4);
    float* shift   = (float*)alloc(256 * 4);
    (void)ws_size; (void)in_sizes; (void)n_in; (void)out_size;

    const int EB = (TOT_E + 255) / 256;

    // ---- build CSR for both edge types (once per call) ----
    hipMemsetAsync(cnt, 0, (size_t)N_NODES * 4, stream);
    count_kernel<<<EB, 256, 0, stream>>>(ei_sp, cnt);
    scan1_kernel<<<SCAN_NB, 256, 0, stream>>>(cnt, offs_sp, bsum);
    scan2_kernel<<<1, 256, 0, stream>>>(bsum, offs_sp + N_NODES);
    scan3_kernel<<<SCAN_NB, 256, 0, stream>>>(offs_sp, bsum);
    hipMemsetAsync(cnt, 0, (size_t)N_NODES * 4, stream);
    scatter_kernel<<<EB, 256, 0, stream>>>(ei_sp, offs_sp, cnt, src_sp);

    hipMemsetAsync(cnt, 0, (size_t)N_NODES * 4, stream);
    count_kernel<<<EB, 256, 0, stream>>>(ei_tp, cnt);
    scan1_kernel<<<SCAN_NB, 256, 0, stream>>>(cnt, offs_tp, bsum);
    scan2_kernel<<<1, 256, 0, stream>>>(bsum, offs_tp + N_NODES);
    scan3_kernel<<<SCAN_NB, 256, 0, stream>>>(offs_tp, bsum);
    hipMemsetAsync(cnt, 0, (size_t)N_NODES * 4, stream);
    scatter_kernel<<<EB, 256, 0, stream>>>(ei_tp, offs_tp, cnt, src_tp);

    // ---- 4 GAT + BN + ReLU layers ----
    const int NB4 = (N_NODES + 3) / 4;             // wave-per-node kernels
    const dim3 ggrid((N_NODES + 127) / 128, 2);    // gemm grid (128x128 tiles)
    for (int L = 0; L < 4; ++L) {
        const float* in = (L == 0) ? x : buf1;
        const int K = (L == 0) ? 128 : 256;
        const int* offs = (L < 2) ? offs_sp : offs_tp;
        const int* ssrc = (L < 2) ? src_sp : src_tp;
        const int base = 3 + L * 6;
        const float* W  = (const float*)d_in[base + 0];
        const float* as_ = (const float*)d_in[base + 1];
        const float* ad_ = (const float*)d_in[base + 2];
        const float* b_  = (const float*)d_in[base + 3];
        const float* g_  = (const float*)d_in[base + 4];
        const float* be_ = (const float*)d_in[base + 5];

        gemm_kernel<<<ggrid, 256, 0, stream>>>(in, W, buf0, N_NODES, K);
        al_kernel<<<NB4, 256, 0, stream>>>(buf0, as_, ad_, als, ald);
        gat_edge_kernel<<<NB4, 256, 0, stream>>>(buf0, offs, ssrc, als, ald, b_, buf1);

        hipMemsetAsync(bnsum, 0, 256 * 8 * 2, stream);
        bn_stats_kernel<<<(N_NODES + 127) / 128, 256, 0, stream>>>(buf1, bnsum, bnsq);
        bn_finalize_kernel<<<1, 256, 0, stream>>>(bnsum, bnsq, g_, be_, scale, shift);
        bn_apply_relu_kernel<<<(N_NODES * 64 + 255) / 256, 256, 0, stream>>>(buf1, scale, shift);
    }

    // ---- final linear ----
    linear_kernel<<<(N_NODES * 32 + 255) / 256, 256, 0, stream>>>(buf1, Wl, bl, (float*)d_out);
}

// Round 5
// 1407.599 us; speedup vs baseline: 1.3444x; 1.0530x over previous
//
#include <hip/hip_runtime.h>
#include <hip/hip_bf16.h>
#include <math.h>

#define N_NODES 50000
#define N_EDGES 800000
#define NH 4
#define HC 256
#define TOT_E (N_EDGES + N_NODES)
#define SCAN_NB ((N_NODES + 255) / 256)

static __device__ __forceinline__ float lrelu(float x) { return x >= 0.f ? x : 0.2f * x; }

// ---------------- CSR build (counting sort by dst) ----------------
__global__ __launch_bounds__(256) void count_kernel(const int* __restrict__ ei,
                                                    int* __restrict__ cnt) {
    int i = blockIdx.x * blockDim.x + threadIdx.x;
    if (i >= TOT_E) return;
    int dst = (i < N_EDGES) ? ei[N_EDGES + i] : (i - N_EDGES);  // self-loops appended
    atomicAdd(&cnt[dst], 1);
}

// device-wide exclusive scan over cnt[N_NODES] -> offs, 3 kernels
__global__ __launch_bounds__(256) void scan1_kernel(const int* __restrict__ cnt,
                                                    int* __restrict__ offs,
                                                    int* __restrict__ bsum) {
    __shared__ int sm[256];
    const int t = threadIdx.x;
    const int base = blockIdx.x * 256;
    int v = (base + t < N_NODES) ? cnt[base + t] : 0;
    sm[t] = v;
    __syncthreads();
#pragma unroll
    for (int d = 1; d < 256; d <<= 1) {
        int add = (t >= d) ? sm[t - d] : 0;
        __syncthreads();
        sm[t] += add;
        __syncthreads();
    }
    if (base + t < N_NODES) offs[base + t] = sm[t] - v;  // local exclusive
    if (t == 255) bsum[blockIdx.x] = sm[255];
}

__global__ __launch_bounds__(256) void scan2_kernel(int* __restrict__ bsum,
                                                    int* __restrict__ total) {
    __shared__ int sm[256];
    const int t = threadIdx.x;
    int v = (t < SCAN_NB) ? bsum[t] : 0;
    sm[t] = v;
    __syncthreads();
#pragma unroll
    for (int d = 1; d < 256; d <<= 1) {
        int add = (t >= d) ? sm[t - d] : 0;
        __syncthreads();
        sm[t] += add;
        __syncthreads();
    }
    if (t < SCAN_NB) bsum[t] = sm[t] - v;  // exclusive block offsets
    if (t == 255) *total = sm[255];        // == TOT_E
}

__global__ __launch_bounds__(256) void scan3_kernel(int* __restrict__ offs,
                                                    const int* __restrict__ bsum) {
    int i = blockIdx.x * blockDim.x + threadIdx.x;
    if (i < N_NODES) offs[i] += bsum[i >> 8];
}

__global__ __launch_bounds__(256) void scatter_kernel(const int* __restrict__ ei,
                                                      const int* __restrict__ offs,
                                                      int* __restrict__ cursor,
                                                      int* __restrict__ ssrc) {
    int i = blockIdx.x * blockDim.x + threadIdx.x;
    if (i >= TOT_E) return;
    int src, dst;
    if (i < N_EDGES) { src = ei[i]; dst = ei[N_EDGES + i]; }
    else             { src = i - N_EDGES; dst = src; }
    int pos = offs[dst] + atomicAdd(&cursor[dst], 1);
    ssrc[pos] = src;
}

// ---------------- fp32 GEMM: C[M,256] = relu(bn(A))[M,K] @ B[K,256] ----------------
// 128x128 tile, 8x8 microtile, 256 threads (16x16).
// Optional fused input BN+ReLU (bnscale/bnshift, nullptr = identity).
// Fused epilogue: als/ald head-dots (exact, no atomics: each (row,head) is
// fully contained in one block since a head spans 64 columns).
__global__ __launch_bounds__(256) void gemm_kernel(const float* __restrict__ A,
                                                   const float* __restrict__ B,
                                                   float* __restrict__ C,
                                                   const float* __restrict__ bnscale,
                                                   const float* __restrict__ bnshift,
                                                   const float* __restrict__ a_s,
                                                   const float* __restrict__ a_d,
                                                   float* __restrict__ als,
                                                   float* __restrict__ ald,
                                                   int M, int K) {
    __shared__ float As[16][128];  // [k][m]
    __shared__ float Bs[16][128];  // [k][n]
    const int t = threadIdx.x;
    const int tx = t & 15, ty = t >> 4;
    const int bm = blockIdx.x * 128;
    const int bn = blockIdx.y * 128;
    const int ar = t >> 2;          // 0..63   A staging row within half
    const int ak = (t & 3) << 2;    // 0,4,8,12
    const int bk = t >> 5;          // 0..7    B staging k within half
    const int bn4 = (t & 31) << 2;  // 0..124
    float acc[8][8] = {{0.f}};
    for (int k0 = 0; k0 < K; k0 += 16) {
        float4 sc = make_float4(1.f, 1.f, 1.f, 1.f);
        float4 sh = make_float4(0.f, 0.f, 0.f, 0.f);
        if (bnscale) {
            sc = *(const float4*)(bnscale + k0 + ak);
            sh = *(const float4*)(bnshift + k0 + ak);
        }
#pragma unroll
        for (int r = 0; r < 2; ++r) {
            int row = bm + r * 64 + ar;
            float4 a4 = make_float4(0.f, 0.f, 0.f, 0.f);
            if (row < M) a4 = *(const float4*)(A + (size_t)row * K + k0 + ak);
            if (bnscale) {  // fused relu(bn(.)) of the previous layer's output
                a4.x = fmaxf(0.f, fmaf(a4.x, sc.x, sh.x));
                a4.y = fmaxf(0.f, fmaf(a4.y, sc.y, sh.y));
                a4.z = fmaxf(0.f, fmaf(a4.z, sc.z, sh.z));
                a4.w = fmaxf(0.f, fmaf(a4.w, sc.w, sh.w));
            }
            As[ak + 0][r * 64 + ar] = a4.x;
            As[ak + 1][r * 64 + ar] = a4.y;
            As[ak + 2][r * 64 + ar] = a4.z;
            As[ak + 3][r * 64 + ar] = a4.w;
        }
#pragma unroll
        for (int r = 0; r < 2; ++r) {
            int kk = r * 8 + bk;
            *(float4*)&Bs[kk][bn4] = *(const float4*)(B + (size_t)(k0 + kk) * HC + bn + bn4);
        }
        __syncthreads();
#pragma unroll
        for (int kk = 0; kk < 16; ++kk) {
            float a[8], b[8];
            *(float4*)&a[0] = *(const float4*)&As[kk][ty * 8];
            *(float4*)&a[4] = *(const float4*)&As[kk][ty * 8 + 4];
            *(float4*)&b[0] = *(const float4*)&Bs[kk][tx * 8];
            *(float4*)&b[4] = *(const float4*)&Bs[kk][tx * 8 + 4];
#pragma unroll
            for (int i = 0; i < 8; ++i)
#pragma unroll
                for (int j = 0; j < 8; ++j)
                    acc[i][j] = fmaf(a[i], b[j], acc[i][j]);
        }
        __syncthreads();
    }
    // C write
#pragma unroll
    for (int i = 0; i < 8; ++i) {
        int row = bm + ty * 8 + i;
        if (row < M) {
            *(float4*)(C + (size_t)row * HC + bn + tx * 8) =
                make_float4(acc[i][0], acc[i][1], acc[i][2], acc[i][3]);
            *(float4*)(C + (size_t)row * HC + bn + tx * 8 + 4) =
                make_float4(acc[i][4], acc[i][5], acc[i][6], acc[i][7]);
        }
    }
    // fused als/ald epilogue: head = (bn>>6) + (tx>>3), cols tx*8..tx*8+7
    const int ch0 = bn + tx * 8;
    float asv[8], adv[8];
#pragma unroll
    for (int j = 0; j < 8; ++j) { asv[j] = a_s[ch0 + j]; adv[j] = a_d[ch0 + j]; }
#pragma unroll
    for (int i = 0; i < 8; ++i) {
        int row = bm + ty * 8 + i;
        float ps = 0.f, pd = 0.f;
#pragma unroll
        for (int j = 0; j < 8; ++j) {
            ps = fmaf(acc[i][j], asv[j], ps);
            pd = fmaf(acc[i][j], adv[j], pd);
        }
#pragma unroll
        for (int d = 1; d < 8; d <<= 1) {  // reduce the 8 lanes of one head-half
            ps += __shfl_xor(ps, d, 64);
            pd += __shfl_xor(pd, d, 64);
        }
        if ((tx & 7) == 0 && row < M) {
            int head = (bn >> 6) + (tx >> 3);
            als[row * NH + head] = ps;
            ald[row * NH + head] = pd;
        }
    }
}

// ---------------- GAT aggregation: one wave per dst, online softmax ----------------
// 4-edge chunks, double-buffered prefetch (keeps 4 h-rows + 4 logits in flight)
__global__ __launch_bounds__(256) void gat_edge_kernel(const float* __restrict__ h,
                                                       const int* __restrict__ offs,
                                                       const int* __restrict__ ssrc,
                                                       const float* __restrict__ als,
                                                       const float* __restrict__ ald,
                                                       const float* __restrict__ bias,
                                                       float* __restrict__ out) {
    const int lane = threadIdx.x & 63;
    const int v = (blockIdx.x << 2) + (threadIdx.x >> 6);
    if (v >= N_NODES) return;
    const int hh = lane >> 4;
    const float aldv = ald[v * NH + hh];
    const int beg = offs[v], end = offs[v + 1];  // degree >= 1 (self-loop)
    float m = -INFINITY, s = 0.f;
    float ax = 0.f, ay = 0.f, az = 0.f, aw = 0.f;

    float4 c0, c1, c2, c3;
    float ca0, ca1, ca2, ca3;
    float4 n0 = make_float4(0.f, 0.f, 0.f, 0.f), n1 = n0, n2 = n0, n3 = n0;
    float na0 = 0.f, na1 = 0.f, na2 = 0.f, na3 = 0.f;

#define GLOAD(HV, AV, IDX)                                         \
    do {                                                           \
        int _i = (IDX); _i = _i < end - 1 ? _i : end - 1;          \
        int _s = ssrc[_i];                                         \
        HV = *(const float4*)(h + (size_t)_s * HC + (lane << 2));  \
        AV = als[_s * NH + hh];                                    \
    } while (0)

#define UPDATE(HV, AV, IDX)                                        \
    do {                                                           \
        float _e = (IDX) < end ? lrelu(AV + aldv) : -INFINITY;     \
        float _mn = fmaxf(m, _e);                                  \
        float _r = __expf(m - _mn);  /* 0 on first edge */         \
        float _ex = __expf(_e - _mn); /* 0 on masked edge */       \
        s = fmaf(s, _r, _ex);                                      \
        ax = fmaf(ax, _r, _ex * HV.x);                             \
        ay = fmaf(ay, _r, _ex * HV.y);                             \
        az = fmaf(az, _r, _ex * HV.z);                             \
        aw = fmaf(aw, _r, _ex * HV.w);                             \
        m = _mn;                                                   \
    } while (0)

    GLOAD(c0, ca0, beg + 0);
    GLOAD(c1, ca1, beg + 1);
    GLOAD(c2, ca2, beg + 2);
    GLOAD(c3, ca3, beg + 3);

    for (int base = beg; base < end; base += 4) {
        const int nb = base + 4;
        if (nb < end) {  // wave-uniform branch: prefetch next chunk
            GLOAD(n0, na0, nb + 0);
            GLOAD(n1, na1, nb + 1);
            GLOAD(n2, na2, nb + 2);
            GLOAD(n3, na3, nb + 3);
        }
        UPDATE(c0, ca0, base + 0);
        UPDATE(c1, ca1, base + 1);
        UPDATE(c2, ca2, base + 2);
        UPDATE(c3, ca3, base + 3);
        c0 = n0; ca0 = na0;
        c1 = n1; ca1 = na1;
        c2 = n2; ca2 = na2;
        c3 = n3; ca3 = na3;
    }
#undef GLOAD
#undef UPDATE

    const float inv = 1.f / (s + 1e-16f);
    float4 b4 = *(const float4*)(bias + (lane << 2));
    *(float4*)(out + (size_t)v * HC + (lane << 2)) =
        make_float4(fmaf(ax, inv, b4.x), fmaf(ay, inv, b4.y),
                    fmaf(az, inv, b4.z), fmaf(aw, inv, b4.w));
}

// ---------------- BatchNorm stats (apply is fused into consumers) ----------------
__global__ __launch_bounds__(256) void bn_stats_kernel(const float* __restrict__ y,
                                                       double* __restrict__ sum,
                                                       double* __restrict__ sqsum) {
    const int t = threadIdx.x;  // channel
    const int r0 = blockIdx.x * 128;
    const int r1 = min(r0 + 128, N_NODES);
    float s = 0.f, q = 0.f;
    for (int r = r0; r < r1; ++r) {
        float v = y[(size_t)r * HC + t];
        s += v;
        q = fmaf(v, v, q);
    }
    atomicAdd(&sum[t], (double)s);
    atomicAdd(&sqsum[t], (double)q);
}

__global__ void bn_finalize_kernel(const double* __restrict__ sum,
                                   const double* __restrict__ sqsum,
                                   const float* __restrict__ g,
                                   const float* __restrict__ be,
                                   float* __restrict__ scale,
                                   float* __restrict__ shift) {
    int t = threadIdx.x;
    double mean = sum[t] / (double)N_NODES;
    double var = sqsum[t] / (double)N_NODES - mean * mean;
    float sc = g[t] * rsqrtf((float)var + 1e-5f);
    scale[t] = sc;
    shift[t] = be[t] - (float)mean * sc;
}

// ---------------- final linear: out[N,32] = relu(bn(y))[N,256] @ Wl[256,32] + bl ----
__global__ __launch_bounds__(256) void linear_kernel(const float* __restrict__ y,
                                                     const float* __restrict__ Wl,
                                                     const float* __restrict__ bl,
                                                     const float* __restrict__ scale,
                                                     const float* __restrict__ shift,
                                                     float* __restrict__ out) {
    __shared__ float Wls[256 * 32];
    __shared__ float scs[256], shs[256];
    const int t = threadIdx.x;
    for (int i = t; i < 256 * 32; i += 256) Wls[i] = Wl[i];
    scs[t] = scale[t];
    shs[t] = shift[t];
    __syncthreads();
    int gid = blockIdx.x * 256 + t;
    if (gid >= N_NODES * 32) return;
    int n = gid >> 5, j = gid & 31;
    float acc = bl[j];
    const float4* yrow = (const float4*)(y + (size_t)n * HC);
#pragma unroll
    for (int k4 = 0; k4 < 64; ++k4) {
        float4 y4 = yrow[k4];
        int k = k4 << 2;
        y4.x = fmaxf(0.f, fmaf(y4.x, scs[k + 0], shs[k + 0]));
        y4.y = fmaxf(0.f, fmaf(y4.y, scs[k + 1], shs[k + 1]));
        y4.z = fmaxf(0.f, fmaf(y4.z, scs[k + 2], shs[k + 2]));
        y4.w = fmaxf(0.f, fmaf(y4.w, scs[k + 3], shs[k + 3]));
        acc = fmaf(y4.x, Wls[(k + 0) * 32 + j], acc);
        acc = fmaf(y4.y, Wls[(k + 1) * 32 + j], acc);
        acc = fmaf(y4.z, Wls[(k + 2) * 32 + j], acc);
        acc = fmaf(y4.w, Wls[(k + 3) * 32 + j], acc);
    }
    out[gid] = acc;
}

extern "C" void kernel_launch(void* const* d_in, const int* in_sizes, int n_in,
                              void* d_out, int out_size, void* d_ws, size_t ws_size,
                              hipStream_t stream) {
    const float* x     = (const float*)d_in[0];
    const int* ei_sp   = (const int*)d_in[1];
    const int* ei_tp   = (const int*)d_in[2];
    const float* Wl    = (const float*)d_in[27];
    const float* bl    = (const float*)d_in[28];

    // ---- workspace layout ----
    char* ws = (char*)d_ws;
    size_t off = 0;
    auto alloc = [&](size_t bytes) -> char* {
        char* p = ws + off;
        off = (off + bytes + 255) & ~(size_t)255;
        return p;
    };
    float* buf0    = (float*)alloc((size_t)N_NODES * HC * 4);  // gemm output h
    float* buf1    = (float*)alloc((size_t)N_NODES * HC * 4);  // gat output / next input
    float* als     = (float*)alloc((size_t)N_NODES * NH * 4);
    float* ald     = (float*)alloc((size_t)N_NODES * NH * 4);
    int*   offs_sp = (int*)alloc((size_t)(N_NODES + 1) * 4);
    int*   offs_tp = (int*)alloc((size_t)(N_NODES + 1) * 4);
    int*   src_sp  = (int*)alloc((size_t)TOT_E * 4);
    int*   src_tp  = (int*)alloc((size_t)TOT_E * 4);
    int*   cnt     = (int*)alloc((size_t)N_NODES * 4);
    int*   bsum    = (int*)alloc((size_t)SCAN_NB * 4);
    double* bnsum  = (double*)alloc(256 * 8 * 2);  // sum + sqsum contiguous
    double* bnsq   = bnsum + 256;
    float* scale   = (float*)alloc(256 * 4);
    float* shift   = (float*)alloc(256 * 4);
    (void)ws_size; (void)in_sizes; (void)n_in; (void)out_size;

    const int EB = (TOT_E + 255) / 256;

    // ---- build CSR for both edge types (once per call) ----
    hipMemsetAsync(cnt, 0, (size_t)N_NODES * 4, stream);
    count_kernel<<<EB, 256, 0, stream>>>(ei_sp, cnt);
    scan1_kernel<<<SCAN_NB, 256, 0, stream>>>(cnt, offs_sp, bsum);
    scan2_kernel<<<1, 256, 0, stream>>>(bsum, offs_sp + N_NODES);
    scan3_kernel<<<SCAN_NB, 256, 0, stream>>>(offs_sp, bsum);
    hipMemsetAsync(cnt, 0, (size_t)N_NODES * 4, stream);
    scatter_kernel<<<EB, 256, 0, stream>>>(ei_sp, offs_sp, cnt, src_sp);

    hipMemsetAsync(cnt, 0, (size_t)N_NODES * 4, stream);
    count_kernel<<<EB, 256, 0, stream>>>(ei_tp, cnt);
    scan1_kernel<<<SCAN_NB, 256, 0, stream>>>(cnt, offs_tp, bsum);
    scan2_kernel<<<1, 256, 0, stream>>>(bsum, offs_tp + N_NODES);
    scan3_kernel<<<SCAN_NB, 256, 0, stream>>>(offs_tp, bsum);
    hipMemsetAsync(cnt, 0, (size_t)N_NODES * 4, stream);
    scatter_kernel<<<EB, 256, 0, stream>>>(ei_tp, offs_tp, cnt, src_tp);

    // ---- 4 GAT + BN(+fused apply) layers ----
    const int NB4 = (N_NODES + 3) / 4;             // wave-per-node kernels
    const dim3 ggrid((N_NODES + 127) / 128, 2);    // gemm grid (128x128 tiles)
    for (int L = 0; L < 4; ++L) {
        const float* in = (L == 0) ? x : buf1;
        const int K = (L == 0) ? 128 : 256;
        const float* bns = (L == 0) ? nullptr : scale;  // prev layer's BN, fused
        const float* bnh = (L == 0) ? nullptr : shift;
        const int* offs = (L < 2) ? offs_sp : offs_tp;
        const int* ssrc = (L < 2) ? src_sp : src_tp;
        const int base = 3 + L * 6;
        const float* W  = (const float*)d_in[base + 0];
        const float* as_ = (const float*)d_in[base + 1];
        const float* ad_ = (const float*)d_in[base + 2];
        const float* b_  = (const float*)d_in[base + 3];
        const float* g_  = (const float*)d_in[base + 4];
        const float* be_ = (const float*)d_in[base + 5];

        gemm_kernel<<<ggrid, 256, 0, stream>>>(in, W, buf0, bns, bnh,
                                               as_, ad_, als, ald, N_NODES, K);
        gat_edge_kernel<<<NB4, 256, 0, stream>>>(buf0, offs, ssrc, als, ald, b_, buf1);

        hipMemsetAsync(bnsum, 0, 256 * 8 * 2, stream);
        bn_stats_kernel<<<(N_NODES + 127) / 128, 256, 0, stream>>>(buf1, bnsum, bnsq);
        bn_finalize_kernel<<<1, 256, 0, stream>>>(bnsum, bnsq, g_, be_, scale, shift);
    }

    // ---- final linear (fused relu(bn(.)) of layer 4) ----
    linear_kernel<<<(N_NODES * 32 + 255) / 256, 256, 0, stream>>>(buf1, Wl, bl,
                                                                  scale, shift,
                                                                  (float*)d_out);
}